// Round 1
// baseline (493.297 us; speedup 1.0000x reference)
//
#include <hip/hip_runtime.h>

// GCN 2-layer: per layer h = X@W; out[i] = b + dinv[i]^2*h[i] + sum_{e:dst=i} dinv[src]*dinv[i]*h[src]
// N=100000 nodes, E=1200000 edges, C=64 channels, fp32 throughout.
// Strategy: build CSR-by-dst once (histogram + scan + scatter), then gather-aggregate
// (wave per node, lane per channel) -> no float atomics in the hot path.

#define NCH 64

// ---------------- utility ----------------
__global__ void zero_int_kernel(int* __restrict__ p, int n) {
    int i = blockIdx.x * blockDim.x + threadIdx.x;
    if (i < n) p[i] = 0;
}

// counts[d] = #edges with dst==d
__global__ void hist_kernel(const int* __restrict__ dst, int* __restrict__ counts, int E) {
    int e = blockIdx.x * blockDim.x + threadIdx.x;
    if (e < E) atomicAdd(&counts[dst[e]], 1);
}

// dinv[i] = rsqrt(counts[i] + 1)   (+1 = self loop)
__global__ void dinv_kernel(const int* __restrict__ counts, float* __restrict__ dinv, int n) {
    int i = blockIdx.x * blockDim.x + threadIdx.x;
    if (i < n) dinv[i] = rsqrtf((float)(counts[i] + 1));
}

// ---------------- exclusive scan (3-phase), chunk = 1024 ----------------
__global__ __launch_bounds__(256) void scanA_kernel(const int* __restrict__ counts,
                                                    int* __restrict__ rowp,
                                                    int* __restrict__ bsums, int n) {
    __shared__ int sh[256];
    int tid = threadIdx.x;
    int base = blockIdx.x * 1024;
    int v[4];
    int ts = 0;
#pragma unroll
    for (int j = 0; j < 4; j++) {
        int idx = base + tid * 4 + j;
        int c = (idx < n) ? counts[idx] : 0;
        v[j] = c; ts += c;
    }
    sh[tid] = ts; __syncthreads();
    for (int off = 1; off < 256; off <<= 1) {
        int t = (tid >= off) ? sh[tid - off] : 0;
        __syncthreads();
        sh[tid] += t;
        __syncthreads();
    }
    int run = sh[tid] - ts;  // exclusive offset within chunk
#pragma unroll
    for (int j = 0; j < 4; j++) {
        run += v[j];
        int idx = base + tid * 4 + j;
        if (idx < n) rowp[idx + 1] = run;  // inclusive-within-chunk at [idx+1]
    }
    if (tid == 255) bsums[blockIdx.x] = sh[255];
}

__global__ __launch_bounds__(128) void scanB_kernel(int* __restrict__ bsums, int nb) {
    __shared__ int sh[128];
    int tid = threadIdx.x;
    int v = (tid < nb) ? bsums[tid] : 0;
    sh[tid] = v; __syncthreads();
    for (int off = 1; off < 128; off <<= 1) {
        int t = (tid >= off) ? sh[tid - off] : 0;
        __syncthreads();
        sh[tid] += t;
        __syncthreads();
    }
    if (tid < nb) bsums[tid] = sh[tid] - v;  // exclusive chunk offsets
}

__global__ void scanC_kernel(int* __restrict__ rowp, const int* __restrict__ bsums, int n) {
    int i = blockIdx.x * blockDim.x + threadIdx.x;
    if (i < n) {
        rowp[i + 1] += bsums[i >> 10];
        if (i == 0) rowp[0] = 0;
    }
}

// scatter edges into CSR buckets; norm precomputed
__global__ void scatter_kernel(const int* __restrict__ src, const int* __restrict__ dst,
                               const int* __restrict__ rowp, int* __restrict__ cursor,
                               const float* __restrict__ dinv,
                               int* __restrict__ csrc, float* __restrict__ cnorm, int E) {
    int e = blockIdx.x * blockDim.x + threadIdx.x;
    if (e < E) {
        int s = src[e], d = dst[e];
        int pos = rowp[d] + atomicAdd(&cursor[d], 1);
        csrc[pos] = s;
        cnorm[pos] = dinv[s] * dinv[d];
    }
}

// ---------------- H = X @ W  (K=M=64, fp32 VALU) ----------------
// block 256 threads: 32 rows/block, each thread computes 8 row-outputs of one column.
__global__ __launch_bounds__(256) void gemm64_kernel(const float* __restrict__ X,
                                                     const float* __restrict__ W,
                                                     float* __restrict__ H, int nrows) {
    __shared__ float Ws[64 * 64];
    __shared__ float Xs[32 * 64];
    int tid = threadIdx.x;
    // stage W (4096 floats) via float4
    const float4* W4 = (const float4*)W;
    float4* Ws4 = (float4*)Ws;
#pragma unroll
    for (int i = 0; i < 4; i++) Ws4[tid + 256 * i] = W4[tid + 256 * i];
    // stage X tile (32x64 = 2048 floats)
    int row0 = blockIdx.x * 32;
    const float4* X4 = (const float4*)(X + (size_t)row0 * NCH);
    float4* Xs4 = (float4*)Xs;
#pragma unroll
    for (int i = 0; i < 2; i++) {
        int idx = tid + 256 * i;
        if (row0 + (idx >> 4) < nrows) Xs4[idx] = X4[idx];
    }
    __syncthreads();

    int col = tid & 63;
    int rg = tid >> 6;  // wave id: whole wave shares rg -> Xs reads are broadcast
    float acc[8] = {0.f, 0.f, 0.f, 0.f, 0.f, 0.f, 0.f, 0.f};
#pragma unroll
    for (int k4 = 0; k4 < 16; k4++) {
        float w0 = Ws[(k4 * 4 + 0) * 64 + col];
        float w1 = Ws[(k4 * 4 + 1) * 64 + col];
        float w2 = Ws[(k4 * 4 + 2) * 64 + col];
        float w3 = Ws[(k4 * 4 + 3) * 64 + col];
#pragma unroll
        for (int r = 0; r < 8; r++) {
            int row = rg * 8 + r;
            float4 xv = *(const float4*)&Xs[row * 64 + k4 * 4];
            acc[r] += xv.x * w0 + xv.y * w1 + xv.z * w2 + xv.w * w3;
        }
    }
#pragma unroll
    for (int r = 0; r < 8; r++) {
        int row = row0 + rg * 8 + r;
        if (row < nrows) H[(size_t)row * NCH + col] = acc[r];
    }
}

// ---------------- gather-aggregate: wave per node, lane per channel ----------------
__global__ __launch_bounds__(256) void aggregate_kernel(const float* __restrict__ H,
                                                        const int* __restrict__ rowp,
                                                        const int* __restrict__ csrc,
                                                        const float* __restrict__ cnorm,
                                                        const float* __restrict__ dinv,
                                                        const float* __restrict__ bias,
                                                        float* __restrict__ out,
                                                        int n, int do_relu) {
    int node = blockIdx.x * 4 + (threadIdx.x >> 6);
    int lane = threadIdx.x & 63;
    if (node >= n) return;
    float di = dinv[node];
    float acc = bias[lane] + di * di * H[(size_t)node * NCH + lane];
    int e = rowp[node];
    int end = rowp[node + 1];
    for (; e + 1 < end; e += 2) {
        int s0 = csrc[e], s1 = csrc[e + 1];
        float w0 = cnorm[e], w1 = cnorm[e + 1];
        acc += w0 * H[(size_t)s0 * NCH + lane];
        acc += w1 * H[(size_t)s1 * NCH + lane];
    }
    if (e < end) acc += cnorm[e] * H[(size_t)csrc[e] * NCH + lane];
    if (do_relu) acc = fmaxf(acc, 0.f);
    out[(size_t)node * NCH + lane] = acc;
}

extern "C" void kernel_launch(void* const* d_in, const int* in_sizes, int n_in,
                              void* d_out, int out_size, void* d_ws, size_t ws_size,
                              hipStream_t stream) {
    const float* x  = (const float*)d_in[0];
    const int* edge = (const int*)d_in[1];
    const float* W1 = (const float*)d_in[2];
    const float* b1 = (const float*)d_in[3];
    const float* W2 = (const float*)d_in[4];
    const float* b2 = (const float*)d_in[5];
    float* out = (float*)d_out;

    const int N = in_sizes[0] / NCH;       // 100000
    const int E = in_sizes[1] / 2;         // 1200000
    const int* src = edge;
    const int* dst = edge + E;

    // workspace layout (all 128B-aligned)
    char* w = (char*)d_ws;
    const size_t SZN = 400128;             // >= N*4, padded
    int*   counts = (int*)(w + 0);
    int*   cursor = (int*)(w + SZN);
    int*   rowp   = (int*)(w + 2 * SZN);   // N+1 ints
    float* dinv   = (float*)(w + 3 * SZN);
    int*   bsums  = (int*)(w + 4 * SZN);   // 128 ints
    int*   csrc   = (int*)(w + 4 * SZN + 512);
    float* cnorm  = (float*)(w + 4 * SZN + 512 + 4800000);
    float* h      = (float*)(w + 4 * SZN + 512 + 2 * 4800000);  // N*64 floats

    const int NB_SCAN = (N + 1023) / 1024;  // 98

    // 1) zero counts + cursor (contiguous 2*SZN bytes)
    {
        int nz = (int)(2 * SZN / 4);
        zero_int_kernel<<<(nz + 255) / 256, 256, 0, stream>>>(counts, nz);
    }
    // 2) degree histogram over dst
    hist_kernel<<<(E + 255) / 256, 256, 0, stream>>>(dst, counts, E);
    // 3) dinv
    dinv_kernel<<<(N + 255) / 256, 256, 0, stream>>>(counts, dinv, N);
    // 4-6) exclusive scan counts -> rowp
    scanA_kernel<<<NB_SCAN, 256, 0, stream>>>(counts, rowp, bsums, N);
    scanB_kernel<<<1, 128, 0, stream>>>(bsums, NB_SCAN);
    scanC_kernel<<<(N + 255) / 256, 256, 0, stream>>>(rowp, bsums, N);
    // 7) scatter into CSR
    scatter_kernel<<<(E + 255) / 256, 256, 0, stream>>>(src, dst, rowp, cursor, dinv,
                                                        csrc, cnorm, E);

    const int GB = (N + 31) / 32;      // gemm blocks
    const int AB = (N + 3) / 4;        // aggregate blocks (4 waves/block)

    // Layer 1: h = x@W1 ; d_out = relu(aggregate(h) + b1)   (d_out used as activation)
    gemm64_kernel<<<GB, 256, 0, stream>>>(x, W1, h, N);
    aggregate_kernel<<<AB, 256, 0, stream>>>(h, rowp, csrc, cnorm, dinv, b1, out, N, 1);
    // Layer 2: h = act@W2 ; d_out = aggregate(h) + b2
    gemm64_kernel<<<GB, 256, 0, stream>>>(out, W2, h, N);
    aggregate_kernel<<<AB, 256, 0, stream>>>(h, rowp, csrc, cnorm, dinv, b2, out, N, 0);
}

// Round 2
// 450.823 us; speedup vs baseline: 1.0942x; 1.0942x over previous
//
#include <hip/hip_runtime.h>

// GCN 2-layer: per layer h = X@W; out[i] = b + dinv[i]^2*h[i] + sum_{e:dst=i} dinv[src]*dinv[i]*h[src]
// N=100000 nodes, E=1200000 edges, C=64 channels, fp32 throughout.
// CSR-by-dst build (histogram + scan + scatter of PACKED (src,norm) int2 pairs),
// then gather-aggregate (wave per node, lane per channel). No float atomics.
// R2: packed int2 CSR (halves scatter write-allocate traffic vs two arrays),
//     aggregate unroll x4 w/ independent accumulators, dinv fused into scanA,
//     zero pass via hipMemsetAsync.

#define NCH 64

// counts[d] = #edges with dst==d
__global__ void hist_kernel(const int* __restrict__ dst, int* __restrict__ counts, int E) {
    int e = blockIdx.x * blockDim.x + threadIdx.x;
    if (e < E) atomicAdd(&counts[dst[e]], 1);
}

// ---------------- exclusive scan (3-phase), chunk = 1024; dinv fused ----------------
__global__ __launch_bounds__(256) void scanA_kernel(const int* __restrict__ counts,
                                                    int* __restrict__ rowp,
                                                    int* __restrict__ bsums,
                                                    float* __restrict__ dinv, int n) {
    __shared__ int sh[256];
    int tid = threadIdx.x;
    int base = blockIdx.x * 1024;
    int v[4];
    int ts = 0;
#pragma unroll
    for (int j = 0; j < 4; j++) {
        int idx = base + tid * 4 + j;
        int c = (idx < n) ? counts[idx] : 0;
        v[j] = c; ts += c;
        if (idx < n) dinv[idx] = rsqrtf((float)(c + 1));  // +1 self loop
    }
    sh[tid] = ts; __syncthreads();
    for (int off = 1; off < 256; off <<= 1) {
        int t = (tid >= off) ? sh[tid - off] : 0;
        __syncthreads();
        sh[tid] += t;
        __syncthreads();
    }
    int run = sh[tid] - ts;  // exclusive offset within chunk
#pragma unroll
    for (int j = 0; j < 4; j++) {
        run += v[j];
        int idx = base + tid * 4 + j;
        if (idx < n) rowp[idx + 1] = run;  // inclusive-within-chunk at [idx+1]
    }
    if (tid == 255) bsums[blockIdx.x] = sh[255];
}

__global__ __launch_bounds__(128) void scanB_kernel(int* __restrict__ bsums, int nb) {
    __shared__ int sh[128];
    int tid = threadIdx.x;
    int v = (tid < nb) ? bsums[tid] : 0;
    sh[tid] = v; __syncthreads();
    for (int off = 1; off < 128; off <<= 1) {
        int t = (tid >= off) ? sh[tid - off] : 0;
        __syncthreads();
        sh[tid] += t;
        __syncthreads();
    }
    if (tid < nb) bsums[tid] = sh[tid] - v;  // exclusive chunk offsets
}

__global__ void scanC_kernel(int* __restrict__ rowp, const int* __restrict__ bsums, int n) {
    int i = blockIdx.x * blockDim.x + threadIdx.x;
    if (i < n) {
        rowp[i + 1] += bsums[i >> 10];
        if (i == 0) rowp[0] = 0;
    }
}

// scatter edges into CSR buckets as packed (src, norm) pairs — single 8B store/edge
__global__ void scatter_kernel(const int* __restrict__ src, const int* __restrict__ dst,
                               const int* __restrict__ rowp, int* __restrict__ cursor,
                               const float* __restrict__ dinv,
                               int2* __restrict__ cpair, int E) {
    int e = blockIdx.x * blockDim.x + threadIdx.x;
    if (e < E) {
        int s = src[e], d = dst[e];
        int pos = rowp[d] + atomicAdd(&cursor[d], 1);
        cpair[pos] = make_int2(s, __float_as_int(dinv[s] * dinv[d]));
    }
}

// ---------------- H = X @ W  (K=M=64, fp32 VALU) ----------------
__global__ __launch_bounds__(256) void gemm64_kernel(const float* __restrict__ X,
                                                     const float* __restrict__ W,
                                                     float* __restrict__ H, int nrows) {
    __shared__ float Ws[64 * 64];
    __shared__ float Xs[32 * 64];
    int tid = threadIdx.x;
    const float4* W4 = (const float4*)W;
    float4* Ws4 = (float4*)Ws;
#pragma unroll
    for (int i = 0; i < 4; i++) Ws4[tid + 256 * i] = W4[tid + 256 * i];
    int row0 = blockIdx.x * 32;
    const float4* X4 = (const float4*)(X + (size_t)row0 * NCH);
    float4* Xs4 = (float4*)Xs;
#pragma unroll
    for (int i = 0; i < 2; i++) {
        int idx = tid + 256 * i;
        if (row0 + (idx >> 4) < nrows) Xs4[idx] = X4[idx];
    }
    __syncthreads();

    int col = tid & 63;
    int rg = tid >> 6;  // wave id: whole wave shares rg -> Xs reads are broadcast
    float acc[8] = {0.f, 0.f, 0.f, 0.f, 0.f, 0.f, 0.f, 0.f};
#pragma unroll
    for (int k4 = 0; k4 < 16; k4++) {
        float w0 = Ws[(k4 * 4 + 0) * 64 + col];
        float w1 = Ws[(k4 * 4 + 1) * 64 + col];
        float w2 = Ws[(k4 * 4 + 2) * 64 + col];
        float w3 = Ws[(k4 * 4 + 3) * 64 + col];
#pragma unroll
        for (int r = 0; r < 8; r++) {
            int row = rg * 8 + r;
            float4 xv = *(const float4*)&Xs[row * 64 + k4 * 4];
            acc[r] += xv.x * w0 + xv.y * w1 + xv.z * w2 + xv.w * w3;
        }
    }
#pragma unroll
    for (int r = 0; r < 8; r++) {
        int row = row0 + rg * 8 + r;
        if (row < nrows) H[(size_t)row * NCH + col] = acc[r];
    }
}

// ---------------- gather-aggregate: wave per node, lane per channel ----------------
// unroll x4, 4 independent accumulators -> 4 gathers in flight
__global__ __launch_bounds__(256) void aggregate_kernel(const float* __restrict__ H,
                                                        const int* __restrict__ rowp,
                                                        const int2* __restrict__ cpair,
                                                        const float* __restrict__ dinv,
                                                        const float* __restrict__ bias,
                                                        float* __restrict__ out,
                                                        int n, int do_relu) {
    int node = blockIdx.x * 4 + (threadIdx.x >> 6);
    int lane = threadIdx.x & 63;
    if (node >= n) return;
    float di = dinv[node];
    float a0 = bias[lane] + di * di * H[(size_t)node * NCH + lane];
    float a1 = 0.f, a2 = 0.f, a3 = 0.f;
    int e = rowp[node];
    int end = rowp[node + 1];
    for (; e + 3 < end; e += 4) {
        int2 p0 = cpair[e];
        int2 p1 = cpair[e + 1];
        int2 p2 = cpair[e + 2];
        int2 p3 = cpair[e + 3];
        float h0 = H[(size_t)p0.x * NCH + lane];
        float h1 = H[(size_t)p1.x * NCH + lane];
        float h2 = H[(size_t)p2.x * NCH + lane];
        float h3 = H[(size_t)p3.x * NCH + lane];
        a0 += __int_as_float(p0.y) * h0;
        a1 += __int_as_float(p1.y) * h1;
        a2 += __int_as_float(p2.y) * h2;
        a3 += __int_as_float(p3.y) * h3;
    }
    for (; e < end; e++) {
        int2 p = cpair[e];
        a0 += __int_as_float(p.y) * H[(size_t)p.x * NCH + lane];
    }
    float acc = (a0 + a1) + (a2 + a3);
    if (do_relu) acc = fmaxf(acc, 0.f);
    out[(size_t)node * NCH + lane] = acc;
}

extern "C" void kernel_launch(void* const* d_in, const int* in_sizes, int n_in,
                              void* d_out, int out_size, void* d_ws, size_t ws_size,
                              hipStream_t stream) {
    const float* x  = (const float*)d_in[0];
    const int* edge = (const int*)d_in[1];
    const float* W1 = (const float*)d_in[2];
    const float* b1 = (const float*)d_in[3];
    const float* W2 = (const float*)d_in[4];
    const float* b2 = (const float*)d_in[5];
    float* out = (float*)d_out;

    const int N = in_sizes[0] / NCH;       // 100000
    const int E = in_sizes[1] / 2;         // 1200000
    const int* src = edge;
    const int* dst = edge + E;

    // workspace layout (16B-aligned blocks)
    char* w = (char*)d_ws;
    const size_t SZN = 400128;             // >= (N+1)*4, padded
    int*   counts = (int*)(w + 0);
    int*   cursor = (int*)(w + SZN);
    int*   rowp   = (int*)(w + 2 * SZN);   // N+1 ints
    float* dinv   = (float*)(w + 3 * SZN);
    int*   bsums  = (int*)(w + 4 * SZN);   // 128 ints
    int2*  cpair  = (int2*)(w + 4 * SZN + 512);               // E pairs = 9.6 MB
    float* h      = (float*)(w + 4 * SZN + 512 + (size_t)E * 8);  // N*64 floats

    const int NB_SCAN = (N + 1023) / 1024;  // 98

    // 1) zero counts + cursor (contiguous 2*SZN bytes)
    hipMemsetAsync(counts, 0, 2 * SZN, stream);
    // 2) degree histogram over dst
    hist_kernel<<<(E + 255) / 256, 256, 0, stream>>>(dst, counts, E);
    // 3-5) exclusive scan counts -> rowp (dinv fused into scanA)
    scanA_kernel<<<NB_SCAN, 256, 0, stream>>>(counts, rowp, bsums, dinv, N);
    scanB_kernel<<<1, 128, 0, stream>>>(bsums, NB_SCAN);
    scanC_kernel<<<(N + 255) / 256, 256, 0, stream>>>(rowp, bsums, N);
    // 6) scatter into packed CSR
    scatter_kernel<<<(E + 255) / 256, 256, 0, stream>>>(src, dst, rowp, cursor, dinv,
                                                        cpair, E);

    const int GB = (N + 31) / 32;      // gemm blocks
    const int AB = (N + 3) / 4;        // aggregate blocks (4 waves/block)

    // Layer 1: h = x@W1 ; d_out = relu(aggregate(h) + b1)   (d_out used as activation)
    gemm64_kernel<<<GB, 256, 0, stream>>>(x, W1, h, N);
    aggregate_kernel<<<AB, 256, 0, stream>>>(h, rowp, cpair, dinv, b1, out, N, 1);
    // Layer 2: h = act@W2 ; d_out = aggregate(h) + b2
    gemm64_kernel<<<GB, 256, 0, stream>>>(out, W2, h, N);
    aggregate_kernel<<<AB, 256, 0, stream>>>(h, rowp, cpair, dinv, b2, out, N, 0);
}